// Round 11
// baseline (120.532 us; speedup 1.0000x reference)
//
#include <hip/hip_runtime.h>

// SobelLoss: mean over 3 dirs of mean |sobel(moved) - sobel(label)|.
// conv(m)-conv(l) = conv(m-l); separable: s=[1,2,1], d=[-1,0,1]:
//   gx = sH(dW) rolled sD;  gy = dH(sW) rolled sD;  gz = sH(sW) rolled -dD.
// R11: float4 loads + pinned depth-1 pipeline. R10 (pinned scalar, 16
// waves/CU) == R7 (unpinned scalar, 32 waves/CU) == ~38 us: scalar dword
// loads move only 3 KB/wave-iter; per-instr cost + latency dominate.
// Now: wave = FULL W row (40 lanes x float4, zero W-overfetch), TH=1,
// global_load_dwordx4 via asm (12 outstanding = 7.7 KB/wave in flight),
// s_waitcnt vmcnt(6) keeps next plane flying, XCD swizzle (lin%8) makes
// halo re-reads same-XCD L2 hits.
// HARD-WON RULES: no min-waves clamp / no waves_per_eu cap (R2/R4 spill,
// R9/R10 occupancy cap); asm loads pin issue order + force liveness.

#define BB 2
#define DD 160
#define HH 192
#define WW 160
#define HW (HH * WW)

#define DC 8                    // output D planes per wave
#define NIT (DC + 2)            // 10
#define NTHREADS 256            // 4 waves/block; wave = 1 output H row

typedef float f4 __attribute__((ext_vector_type(4)));

#define GLOAD4(dst, vo, base) \
    asm volatile("global_load_dwordx4 %0, %1, %2" \
                 : "=v"(dst) : "v"(vo), "s"(base) : "memory")

__global__ __launch_bounds__(NTHREADS)
void sobel_loss_kernel(const float* __restrict__ moved,
                       const float* __restrict__ label,
                       float* __restrict__ out)
{
    __shared__ float red[4];

    const int tid  = threadIdx.x;
    const int lane = tid & 63;
    const int wvi  = tid >> 6;                  // 0..3

    // ---- XCD swizzle: xcd = lin%8 owns H-slab [6x*4 .. ) for all D,b ----
    const int lin = blockIdx.x;                 // 0..1919
    const int xcd = lin & 7;
    const int sl  = lin >> 3;                   // 0..239
    const int hg  = xcd * 6 + (sl % 6);         // 0..47 (H group of 4 rows)
    const int t   = sl / 6;                     // 0..39
    const int dch = t % 20;
    const int b   = t / 20;

    const int h      = hg * 4 + wvi;            // output row 0..191
    const int d0     = dch * DC;
    const int base_b = b * (DD * HW);

    const int  wcol = min(lane, 39) * 4;        // float col (lanes>=40 clamp)
    const bool outl = lane < 40;

    // per-row byte voffsets (wave-uniform validity; fixed across D)
    int  vo[3];
    bool rv[3];
#pragma unroll
    for (int r = 0; r < 3; ++r) {
        const int gh = h - 1 + r;
        rv[r] = (unsigned)gh < (unsigned)HH;    // wave-uniform (TH=1)
        vo[r] = (min(max(gh, 0), HH - 1) * WW + wcol) * 4;
    }

    f4 bm[2][3], bl[2][3];                      // 2 slots x 3 rows
    {   // prologue: plane d0-1 (clamped) -> slot 0
        const float* pm = moved + base_b + max(d0 - 1, 0) * HW;
        const float* pl = label + base_b + max(d0 - 1, 0) * HW;
        GLOAD4(bm[0][0], vo[0], pm); GLOAD4(bm[0][1], vo[1], pm);
        GLOAD4(bm[0][2], vo[2], pm);
        GLOAD4(bl[0][0], vo[0], pl); GLOAD4(bl[0][1], vo[1], pl);
        GLOAD4(bl[0][2], vo[2], pl);
    }   // outstanding: 6

    f4 px1 = {0,0,0,0}, px2 = px1, py1 = px1, py2 = px1, pz1 = px1, pz2 = px1;
    f4 acc = {0,0,0,0};

#pragma unroll
    for (int it = 0; it < NIT; ++it) {
        const int s = it & 1, n = s ^ 1;

        if (it + 1 < NIT) {
            // issue next plane into the other slot (last read at it-1)
            const int p = min(d0 + it, DD - 1);
            const float* pm = moved + base_b + p * HW;
            const float* pl = label + base_b + p * HW;
            GLOAD4(bm[n][0], vo[0], pm); GLOAD4(bm[n][1], vo[1], pm);
            GLOAD4(bm[n][2], vo[2], pm);
            GLOAD4(bl[n][0], vo[0], pl); GLOAD4(bl[n][1], vo[1], pl);
            GLOAD4(bl[n][2], vo[2], pl);
            // wait ONLY the oldest 6 (slot s); 6 stay in flight
            asm volatile("s_waitcnt vmcnt(6)"
                : "+v"(bm[s][0]), "+v"(bm[s][1]), "+v"(bm[s][2]),
                  "+v"(bl[s][0]), "+v"(bl[s][1]), "+v"(bl[s][2]));
        } else {
            asm volatile("s_waitcnt vmcnt(0)"
                : "+v"(bm[s][0]), "+v"(bm[s][1]), "+v"(bm[s][2]),
                  "+v"(bl[s][0]), "+v"(bl[s][1]), "+v"(bl[s][2])
                :: "memory");
        }

        // ---- compute plane p = d0-1+it ----
        const bool pv = (unsigned)(d0 - 1 + it) < (unsigned)DD;
        f4 sW[3], dW[3];
#pragma unroll
        for (int r = 0; r < 3; ++r) {
            f4 d = bm[s][r] - bl[s][r];
            if (!(pv && rv[r])) d = f4{0,0,0,0};        // wave-uniform branch
            float dl = __shfl_up(d.w, 1, 64);           // col 4l-1
            float dr = __shfl_down(d.x, 1, 64);         // col 4l+4
            if (lane == 0)  dl = 0.f;                   // col -1
            if (lane == 39) dr = 0.f;                   // col 160
            sW[r].x = dl  + 2.f * d.x + d.y;
            sW[r].y = d.x + 2.f * d.y + d.z;
            sW[r].z = d.y + 2.f * d.z + d.w;
            sW[r].w = d.z + 2.f * d.w + dr;
            dW[r].x = d.y - dl;
            dW[r].y = d.z - d.x;
            dW[r].z = d.w - d.y;
            dW[r].w = dr  - d.z;
        }
        const f4 pxp = dW[0] + 2.f * dW[1] + dW[2];     // sH(dW)
        const f4 pzp = sW[0] + 2.f * sW[1] + sW[2];     // sH(sW)
        const f4 pyp = sW[2] - sW[0];                   // dH(sW)
        if (it >= 2) {   // output plane q = d0+it-2
            const f4 gx = px2 + 2.f * px1 + pxp;        // sD
            const f4 gy = py2 + 2.f * py1 + pyp;        // sD
            const f4 gz = pz2 - pzp;                    // dD: (q-1)-(q+1)
            acc.x += __builtin_fabsf(gx.x) + __builtin_fabsf(gy.x) + __builtin_fabsf(gz.x);
            acc.y += __builtin_fabsf(gx.y) + __builtin_fabsf(gy.y) + __builtin_fabsf(gz.y);
            acc.z += __builtin_fabsf(gx.z) + __builtin_fabsf(gy.z) + __builtin_fabsf(gz.z);
            acc.w += __builtin_fabsf(gx.w) + __builtin_fabsf(gy.w) + __builtin_fabsf(gz.w);
        }
        px2 = px1; px1 = pxp;
        py2 = py1; py1 = pyp;
        pz2 = pz1; pz1 = pzp;
    }

    // ---- reduce: mask idle lanes, wave shuffle -> LDS -> one atomic ----
    if (!outl) acc = f4{0,0,0,0};
    float a = (acc.x + acc.y) + (acc.z + acc.w);
#pragma unroll
    for (int off = 32; off > 0; off >>= 1)
        a += __shfl_down(a, off, 64);
    if (lane == 0) red[wvi] = a;
    __syncthreads();
    if (tid == 0) {
        const float s = red[0] + red[1] + red[2] + red[3];
        atomicAdd(out, s * (1.0f / (3.0f * BB * DD * HH * WW)));
    }
}

extern "C" void kernel_launch(void* const* d_in, const int* in_sizes, int n_in,
                              void* d_out, int out_size, void* d_ws, size_t ws_size,
                              hipStream_t stream) {
    const float* moved = (const float*)d_in[0];
    const float* label = (const float*)d_in[1];
    float* out = (float*)d_out;
    (void)in_sizes; (void)n_in; (void)out_size; (void)d_ws; (void)ws_size;

    hipMemsetAsync(out, 0, sizeof(float), stream);
    // 48 H-groups x 20 D-chunks x 2 batches = 1920 blocks (XCD-swizzled)
    sobel_loss_kernel<<<dim3(1920), NTHREADS, 0, stream>>>(moved, label, out);
}